// Round 14
// baseline (444.447 us; speedup 1.0000x reference)
//
#include <hip/hip_runtime.h>
#include <hip/hip_cooperative_groups.h>
#include <math.h>

namespace cg = cooperative_groups;

#define D 64
#define SCAN_TILE 1024
#define SCAN_THREADS 256
#define SCAN_ITEMS 4
#define HS 16          // hist padding stride (fallback path only)
#define BSHIFT 9       // bucket = id >> 9 (512 nodes per bucket)
#define BW 512
#define CHUNK 4096     // edges per bucketing block

// ---------------------------------------------------------------------------
// bf16 helpers (packed 2 x bf16 per uint; RNE rounding)
// ---------------------------------------------------------------------------
__device__ __forceinline__ unsigned pack_bf16(float a, float b) {
    unsigned ua = __float_as_uint(a);
    unsigned ub = __float_as_uint(b);
    ua = (ua + 0x7fffu + ((ua >> 16) & 1u)) >> 16;
    ub = (ub + 0x7fffu + ((ub >> 16) & 1u)) >> 16;
    return ua | (ub << 16);
}
__device__ __forceinline__ float blo(unsigned u) { return __uint_as_float(u << 16); }
__device__ __forceinline__ float bhi(unsigned u) { return __uint_as_float(u & 0xffff0000u); }

// ============================================================================
// R14: SINGLE cooperative prologue kernel — phases separated by grid.sync():
//   P1 count (int4)  P2 per-bucket chunk-scan  P3 base scan  P4 scatter (int4)
//   P5 finalize (offsets + norms + placement)
// Grid must be exactly 2*NBv blocks x 256 threads.
// ============================================================================
__global__ __launch_bounds__(256)
void csr_build_coop_kernel(const int* __restrict__ src, const int* __restrict__ dst,
                           int* __restrict__ bcnt_d, int* __restrict__ bcnt_s,
                           int* __restrict__ bstart_d, int* __restrict__ bstart_s,
                           int* __restrict__ btot_d, int* __restrict__ btot_s,
                           int* __restrict__ bbeg_d, int* __restrict__ bbeg_s,
                           unsigned* __restrict__ bucketed_d,
                           unsigned short* __restrict__ bucketed_s,
                           int* __restrict__ offsets, float* __restrict__ norm_dst,
                           float* __restrict__ norm_src, int* __restrict__ sorted_src,
                           int N, int E, int NBv, int nChunks) {
    cg::grid_group grid = cg::this_grid();
    __shared__ int sA[512];
    __shared__ int sB[512];
    __shared__ int sC[256];
    const int t = threadIdx.x;

    // ---- P1: per-chunk dual bucket count (int4 index reads)
    for (int c = blockIdx.x; c < nChunks; c += gridDim.x) {
        sA[t] = 0; sA[t + 256] = 0;
        __syncthreads();
        int beg = c * CHUNK;
        int end = beg + CHUNK; if (end > E) end = E;
        int n4 = (end - beg) >> 2;
        const int4* s4 = reinterpret_cast<const int4*>(src + beg);
        const int4* d4 = reinterpret_cast<const int4*>(dst + beg);
        for (int j = t; j < n4; j += 256) {
            int4 dv = d4[j];
            int4 sv = s4[j];
            atomicAdd(&sA[dv.x >> BSHIFT], 1);
            atomicAdd(&sA[dv.y >> BSHIFT], 1);
            atomicAdd(&sA[dv.z >> BSHIFT], 1);
            atomicAdd(&sA[dv.w >> BSHIFT], 1);
            atomicAdd(&sA[256 + (sv.x >> BSHIFT)], 1);
            atomicAdd(&sA[256 + (sv.y >> BSHIFT)], 1);
            atomicAdd(&sA[256 + (sv.z >> BSHIFT)], 1);
            atomicAdd(&sA[256 + (sv.w >> BSHIFT)], 1);
        }
        for (int j = beg + (n4 << 2) + t; j < end; j += 256) {
            atomicAdd(&sA[dst[j] >> BSHIFT], 1);
            atomicAdd(&sA[256 + (src[j] >> BSHIFT)], 1);
        }
        __syncthreads();
        for (int i = t; i < NBv; i += 256) {
            bcnt_d[(size_t)c * NBv + i] = sA[i];
            bcnt_s[(size_t)c * NBv + i] = sA[256 + i];
        }
        __syncthreads();
    }
    __threadfence();
    grid.sync();

    // ---- P2: per-bucket scan over the chunk axis (block = bucket column)
    if ((int)blockIdx.x < 2 * NBv) {
        int which = ((int)blockIdx.x >= NBv) ? 1 : 0;
        int b = (int)blockIdx.x - which * NBv;
        const int* bcnt = which ? bcnt_s : bcnt_d;
        int* bstart     = which ? bstart_s : bstart_d;
        int* btot       = which ? btot_s : btot_d;
        int carry = 0;
        for (int c0 = 0; c0 < nChunks; c0 += 256) {
            int c = c0 + t;
            int v = (c < nChunks) ? bcnt[(size_t)c * NBv + b] : 0;
            sC[t] = v;
            __syncthreads();
            for (int off = 1; off < 256; off <<= 1) {
                int val = (t >= off) ? sC[t - off] : 0;
                __syncthreads();
                if (t >= off) sC[t] += val;
                __syncthreads();
            }
            if (c < nChunks) bstart[(size_t)c * NBv + b] = carry + sC[t] - v;
            carry += sC[255];
            __syncthreads();
        }
        if (t == 0) btot[b] = carry;
    }
    __threadfence();
    grid.sync();

    // ---- P3: exclusive scan of btot -> bucket bases (blocks 0 and 1)
    if (blockIdx.x < 2) {
        const int* btot = (blockIdx.x == 0) ? btot_d : btot_s;
        int* bbeg       = (blockIdx.x == 0) ? bbeg_d : bbeg_s;
        int v = (t < NBv) ? btot[t] : 0;
        sC[t] = v;
        __syncthreads();
        for (int off = 1; off < 256; off <<= 1) {
            int val = (t >= off) ? sC[t - off] : 0;
            __syncthreads();
            if (t >= off) sC[t] += val;
            __syncthreads();
        }
        if (t < NBv) bbeg[t] = sC[t] - v;
        if (t == 0) bbeg[NBv] = E;
    }
    __threadfence();
    grid.sync();

    // ---- P4: scatter into bucket-contiguous runs (int4 index reads)
    for (int c = blockIdx.x; c < nChunks; c += gridDim.x) {
        for (int i = t; i < NBv; i += 256) {
            sB[i]       = bstart_d[(size_t)c * NBv + i] + bbeg_d[i];
            sB[256 + i] = bstart_s[(size_t)c * NBv + i] + bbeg_s[i];
        }
        __syncthreads();
        int beg = c * CHUNK;
        int end = beg + CHUNK; if (end > E) end = E;
        int n4 = (end - beg) >> 2;
        const int4* s4 = reinterpret_cast<const int4*>(src + beg);
        const int4* d4 = reinterpret_cast<const int4*>(dst + beg);
        for (int j = t; j < n4; j += 256) {
            int4 dv = d4[j];
            int4 sv = s4[j];
            int pd, ps;
            pd = atomicAdd(&sB[dv.x >> BSHIFT], 1);
            bucketed_d[pd] = ((unsigned)(dv.x & (BW - 1)) << 17) | (unsigned)sv.x;
            pd = atomicAdd(&sB[dv.y >> BSHIFT], 1);
            bucketed_d[pd] = ((unsigned)(dv.y & (BW - 1)) << 17) | (unsigned)sv.y;
            pd = atomicAdd(&sB[dv.z >> BSHIFT], 1);
            bucketed_d[pd] = ((unsigned)(dv.z & (BW - 1)) << 17) | (unsigned)sv.z;
            pd = atomicAdd(&sB[dv.w >> BSHIFT], 1);
            bucketed_d[pd] = ((unsigned)(dv.w & (BW - 1)) << 17) | (unsigned)sv.w;
            ps = atomicAdd(&sB[256 + (sv.x >> BSHIFT)], 1);
            bucketed_s[ps] = (unsigned short)(sv.x & (BW - 1));
            ps = atomicAdd(&sB[256 + (sv.y >> BSHIFT)], 1);
            bucketed_s[ps] = (unsigned short)(sv.y & (BW - 1));
            ps = atomicAdd(&sB[256 + (sv.z >> BSHIFT)], 1);
            bucketed_s[ps] = (unsigned short)(sv.z & (BW - 1));
            ps = atomicAdd(&sB[256 + (sv.w >> BSHIFT)], 1);
            bucketed_s[ps] = (unsigned short)(sv.w & (BW - 1));
        }
        for (int j = beg + (n4 << 2) + t; j < end; j += 256) {
            int d = dst[j], s = src[j];
            int pd = atomicAdd(&sB[d >> BSHIFT], 1);
            bucketed_d[pd] = ((unsigned)(d & (BW - 1)) << 17) | (unsigned)s;
            int ps = atomicAdd(&sB[256 + (s >> BSHIFT)], 1);
            bucketed_s[ps] = (unsigned short)(s & (BW - 1));
        }
        __syncthreads();
    }
    __threadfence();
    grid.sync();

    // ---- P5: finalize. dst blocks: count -> 512-wide scan -> offsets + norm_dst
    //      + placement. src blocks: count -> norm_src.
    if ((int)blockIdx.x < NBv) {
        int b = blockIdx.x;
        sA[t] = 0; sA[t + 256] = 0;
        __syncthreads();
        int beg = bbeg_d[b], end = bbeg_d[b + 1];
        for (int j = beg + t; j < end; j += 256)
            atomicAdd(&sA[bucketed_d[j] >> 17], 1);
        __syncthreads();
        int c0 = sA[2 * t], c1 = sA[2 * t + 1];
        sC[t] = c0 + c1;
        __syncthreads();
        for (int off = 1; off < 256; off <<= 1) {
            int v = (t >= off) ? sC[t - off] : 0;
            __syncthreads();
            if (t >= off) sC[t] += v;
            __syncthreads();
        }
        int excl = sC[t] - (c0 + c1);
        int off0 = beg + excl;
        int off1 = off0 + c0;
        int dbase = b << BSHIFT;
        int d0 = dbase + 2 * t, d1 = dbase + 2 * t + 1;
        sB[2 * t] = off0; sB[2 * t + 1] = off1;
        if (d0 < N) {
            offsets[d0] = off0;
            norm_dst[d0] = 1.0f / sqrtf((float)(c0 < 1 ? 1 : c0));
        }
        if (d1 < N) {
            offsets[d1] = off1;
            norm_dst[d1] = 1.0f / sqrtf((float)(c1 < 1 ? 1 : c1));
        }
        if (b == NBv - 1 && t == 0) offsets[N] = E;
        __syncthreads();
        for (int j = beg + t; j < end; j += 256) {
            unsigned v = bucketed_d[j];
            int pos = atomicAdd(&sB[v >> 17], 1);
            sorted_src[pos] = (int)(v & 0x1FFFFu);
        }
    } else if ((int)blockIdx.x < 2 * NBv) {
        int b = (int)blockIdx.x - NBv;
        sA[t] = 0; sA[t + 256] = 0;
        __syncthreads();
        int beg = bbeg_s[b], end = bbeg_s[b + 1];
        for (int j = beg + t; j < end; j += 256)
            atomicAdd(&sA[bucketed_s[j]], 1);
        __syncthreads();
        int sbase = b << BSHIFT;
        for (int i = t; i < BW; i += 256) {
            int s = sbase + i;
            if (s < N) {
                int c = sA[i];
                norm_src[s] = 1.0f / sqrtf((float)(c < 1 ? 1 : c));
            }
        }
    }
}

// ============================================================================
// Non-coop prologue kernels (R13 proven — used when coop launch unavailable)
// ============================================================================

__global__ __launch_bounds__(256)
void bucket_count_chunks2_kernel(const int* __restrict__ src, const int* __restrict__ dst,
                                 int* __restrict__ bcnt_d, int* __restrict__ bcnt_s,
                                 int E, int NBv) {
    __shared__ int cd[256];
    __shared__ int cs[256];
    for (int i = threadIdx.x; i < NBv; i += 256) { cd[i] = 0; cs[i] = 0; }
    __syncthreads();
    int beg = blockIdx.x * CHUNK;
    int end = beg + CHUNK; if (end > E) end = E;
    for (int j = beg + threadIdx.x; j < end; j += 256) {
        atomicAdd(&cd[dst[j] >> BSHIFT], 1);
        atomicAdd(&cs[src[j] >> BSHIFT], 1);
    }
    __syncthreads();
    for (int i = threadIdx.x; i < NBv; i += 256) {
        bcnt_d[(size_t)blockIdx.x * NBv + i] = cd[i];
        bcnt_s[(size_t)blockIdx.x * NBv + i] = cs[i];
    }
}

__global__ __launch_bounds__(256)
void bucket_scan_chunks2_kernel(const int* __restrict__ bcnt_d, int* __restrict__ bstart_d,
                                int* __restrict__ btot_d,
                                const int* __restrict__ bcnt_s, int* __restrict__ bstart_s,
                                int* __restrict__ btot_s,
                                int nChunks, int NBv) {
    __shared__ int sdata[256];
    int which = (blockIdx.x >= NBv) ? 1 : 0;
    int b = blockIdx.x - which * NBv;
    const int* bcnt   = which ? bcnt_s : bcnt_d;
    int*       bstart = which ? bstart_s : bstart_d;
    int*       btot   = which ? btot_s : btot_d;
    int t = threadIdx.x;
    int carry = 0;
    for (int c0 = 0; c0 < nChunks; c0 += 256) {
        int c = c0 + t;
        int v = (c < nChunks) ? bcnt[(size_t)c * NBv + b] : 0;
        sdata[t] = v;
        __syncthreads();
        for (int off = 1; off < 256; off <<= 1) {
            int val = (t >= off) ? sdata[t - off] : 0;
            __syncthreads();
            if (t >= off) sdata[t] += val;
            __syncthreads();
        }
        if (c < nChunks) bstart[(size_t)c * NBv + b] = carry + sdata[t] - v;
        carry += sdata[255];
        __syncthreads();
    }
    if (t == 0) btot[b] = carry;
}

__global__ __launch_bounds__(256)
void bucket_base2_kernel(const int* __restrict__ btot_d, int* __restrict__ bbeg_d,
                         const int* __restrict__ btot_s, int* __restrict__ bbeg_s,
                         int NBv, int E) {
    __shared__ int sdata[256];
    const int* btot = (blockIdx.x == 0) ? btot_d : btot_s;
    int*       bbeg = (blockIdx.x == 0) ? bbeg_d : bbeg_s;
    int t = threadIdx.x;
    int v = (t < NBv) ? btot[t] : 0;
    sdata[t] = v;
    __syncthreads();
    for (int off = 1; off < 256; off <<= 1) {
        int val = (t >= off) ? sdata[t - off] : 0;
        __syncthreads();
        if (t >= off) sdata[t] += val;
        __syncthreads();
    }
    if (t < NBv) bbeg[t] = sdata[t] - v;
    if (t == 0) bbeg[NBv] = E;
}

__global__ __launch_bounds__(256)
void bucket_scatter2_kernel(const int* __restrict__ src, const int* __restrict__ dst,
                            const int* __restrict__ bstart_d, const int* __restrict__ bbeg_d,
                            const int* __restrict__ bstart_s, const int* __restrict__ bbeg_s,
                            unsigned* __restrict__ bucketed_d,
                            unsigned short* __restrict__ bucketed_s,
                            int E, int NBv) {
    __shared__ int cur_d[256];
    __shared__ int cur_s[256];
    for (int i = threadIdx.x; i < NBv; i += 256) {
        cur_d[i] = bstart_d[(size_t)blockIdx.x * NBv + i] + bbeg_d[i];
        cur_s[i] = bstart_s[(size_t)blockIdx.x * NBv + i] + bbeg_s[i];
    }
    __syncthreads();
    int beg = blockIdx.x * CHUNK;
    int end = beg + CHUNK; if (end > E) end = E;
    for (int j = beg + threadIdx.x; j < end; j += 256) {
        int d = dst[j];
        int s = src[j];
        int pd = atomicAdd(&cur_d[d >> BSHIFT], 1);
        bucketed_d[pd] = ((unsigned)(d & (BW - 1)) << 17) | (unsigned)s;
        int ps = atomicAdd(&cur_s[s >> BSHIFT], 1);
        bucketed_s[ps] = (unsigned short)(s & (BW - 1));
    }
}

__global__ __launch_bounds__(256)
void bucket_finalize_kernel(const unsigned* __restrict__ bucketed_d,
                            const int* __restrict__ bbeg_d,
                            const unsigned short* __restrict__ bucketed_s,
                            const int* __restrict__ bbeg_s,
                            int* __restrict__ offsets, float* __restrict__ norm_dst,
                            float* __restrict__ norm_src, int* __restrict__ sorted_src,
                            int N, int E, int NBv) {
    __shared__ int cnt[BW];
    __shared__ int cur[BW];
    __shared__ int ssum[256];
    int t = threadIdx.x;
    if (blockIdx.x < NBv) {
        int b = blockIdx.x;
        cnt[t] = 0; cnt[t + 256] = 0;
        __syncthreads();
        int beg = bbeg_d[b], end = bbeg_d[b + 1];
        for (int j = beg + t; j < end; j += 256)
            atomicAdd(&cnt[bucketed_d[j] >> 17], 1);
        __syncthreads();
        int c0 = cnt[2 * t], c1 = cnt[2 * t + 1];
        ssum[t] = c0 + c1;
        __syncthreads();
        for (int off = 1; off < 256; off <<= 1) {
            int v = (t >= off) ? ssum[t - off] : 0;
            __syncthreads();
            if (t >= off) ssum[t] += v;
            __syncthreads();
        }
        int excl = ssum[t] - (c0 + c1);
        int off0 = beg + excl;
        int off1 = off0 + c0;
        int dbase = b << BSHIFT;
        int d0 = dbase + 2 * t, d1 = dbase + 2 * t + 1;
        cur[2 * t] = off0; cur[2 * t + 1] = off1;
        if (d0 < N) {
            offsets[d0] = off0;
            norm_dst[d0] = 1.0f / sqrtf((float)(c0 < 1 ? 1 : c0));
        }
        if (d1 < N) {
            offsets[d1] = off1;
            norm_dst[d1] = 1.0f / sqrtf((float)(c1 < 1 ? 1 : c1));
        }
        if (b == NBv - 1 && t == 0) offsets[N] = E;
        __syncthreads();
        for (int j = beg + t; j < end; j += 256) {
            unsigned v = bucketed_d[j];
            int pos = atomicAdd(&cur[v >> 17], 1);
            sorted_src[pos] = (int)(v & 0x1FFFFu);
        }
    } else {
        int b = blockIdx.x - NBv;
        cnt[t] = 0; cnt[t + 256] = 0;
        __syncthreads();
        int beg = bbeg_s[b], end = bbeg_s[b + 1];
        for (int j = beg + t; j < end; j += 256)
            atomicAdd(&cnt[bucketed_s[j]], 1);
        __syncthreads();
        int sbase = b << BSHIFT;
        for (int i = t; i < BW; i += 256) {
            int s = sbase + i;
            if (s < N) {
                int c = cnt[i];
                norm_src[s] = 1.0f / sqrtf((float)(c < 1 ? 1 : c));
            }
        }
    }
}

// ============================================================================
// Scans (fallback path only)
// ============================================================================

__global__ __launch_bounds__(SCAN_THREADS)
void scan_blocks_kernel(const int* __restrict__ cnt_dst, int* __restrict__ offsets,
                        int* __restrict__ partials, int N, int S) {
    __shared__ int sdata[SCAN_THREADS];
    int t = threadIdx.x;
    int base = blockIdx.x * SCAN_TILE + t * SCAN_ITEMS;
    int v[SCAN_ITEMS];
    int sum = 0;
    #pragma unroll
    for (int i = 0; i < SCAN_ITEMS; ++i) {
        int idx = base + i;
        v[i] = (idx < N) ? cnt_dst[(size_t)idx * S] : 0;
        sum += v[i];
    }
    sdata[t] = sum;
    __syncthreads();
    for (int off = 1; off < SCAN_THREADS; off <<= 1) {
        int val = (t >= off) ? sdata[t - off] : 0;
        __syncthreads();
        if (t >= off) sdata[t] += val;
        __syncthreads();
    }
    int excl = sdata[t] - sum;
    if (t == SCAN_THREADS - 1) partials[blockIdx.x] = sdata[t];
    int run = excl;
    #pragma unroll
    for (int i = 0; i < SCAN_ITEMS; ++i) {
        int idx = base + i;
        if (idx < N) offsets[idx] = run;
        run += v[i];
    }
}

__global__ __launch_bounds__(SCAN_THREADS)
void scan_partials_kernel(int* __restrict__ partials, int nblk) {
    __shared__ int sdata[SCAN_THREADS];
    int t = threadIdx.x;
    int v = (t < nblk) ? partials[t] : 0;
    sdata[t] = v;
    __syncthreads();
    for (int off = 1; off < SCAN_THREADS; off <<= 1) {
        int val = (t >= off) ? sdata[t - off] : 0;
        __syncthreads();
        if (t >= off) sdata[t] += val;
        __syncthreads();
    }
    if (t < nblk) partials[t] = sdata[t] - v;
}

__global__ void add_back_kernel(int* __restrict__ offsets, int* __restrict__ cursor,
                                const int* __restrict__ partials, int N, int E, int S) {
    int i = blockIdx.x * blockDim.x + threadIdx.x;
    if (i < N) {
        int o = offsets[i] + partials[i >> 10];
        offsets[i] = o;
        cursor[(size_t)i * S] = o;
    }
    if (i == 0) offsets[N] = E;
}

// ============================================================================
// y = (x*norm_src)@W  (bf16-packed y) — register-tiled GEMM (R9 occupancy-fixed)
// ============================================================================

#define XW_ROWS 64
#define ATP 68   // padded row stride (floats)

__global__ __launch_bounds__(256, 4)
void xw_tiled_kernel(const float4* __restrict__ x4, const float* __restrict__ W,
                     const float* __restrict__ norm_src, unsigned* __restrict__ y, int N) {
    __shared__ float Ws[D * D];       // W[k][f], row-major
    __shared__ float At[D][ATP];      // At[k][local row]
    int t = threadIdx.x;

    for (int i = t; i < D * D / 4; i += 256)
        reinterpret_cast<float4*>(Ws)[i] = reinterpret_cast<const float4*>(W)[i];

    int rowbase = blockIdx.x * XW_ROWS;
    int lr = t >> 2;
    int qc = t & 3;
    int gr = rowbase + lr;
    float ns = (gr < N) ? norm_src[gr] : 0.0f;
    #pragma unroll
    for (int c = qc; c < 16; c += 4) {
        float4 v = (gr < N) ? x4[(size_t)gr * 16 + c] : make_float4(0.f, 0.f, 0.f, 0.f);
        At[c * 4 + 0][lr] = v.x * ns;
        At[c * 4 + 1][lr] = v.y * ns;
        At[c * 4 + 2][lr] = v.z * ns;
        At[c * 4 + 3][lr] = v.w * ns;
    }
    __syncthreads();

    int tx = t & 15;
    int ty = t >> 4;
    float4 acc0 = make_float4(0.f, 0.f, 0.f, 0.f);
    float4 acc1 = acc0, acc2 = acc0, acc3 = acc0;
    #pragma unroll 4
    for (int k = 0; k < D; ++k) {
        float4 a = *reinterpret_cast<const float4*>(&At[k][ty * 4]);
        float4 w = *reinterpret_cast<const float4*>(&Ws[k * D + tx * 4]);
        acc0.x += a.x * w.x; acc0.y += a.x * w.y; acc0.z += a.x * w.z; acc0.w += a.x * w.w;
        acc1.x += a.y * w.x; acc1.y += a.y * w.y; acc1.z += a.y * w.z; acc1.w += a.y * w.w;
        acc2.x += a.z * w.x; acc2.y += a.z * w.y; acc2.z += a.z * w.z; acc2.w += a.z * w.w;
        acc3.x += a.w * w.x; acc3.y += a.w * w.y; acc3.z += a.w * w.z; acc3.w += a.w * w.w;
    }

    uint2* y2 = reinterpret_cast<uint2*>(y);
    int r0 = rowbase + ty * 4;
    if (r0 + 0 < N) y2[(size_t)(r0 + 0) * 16 + tx] =
        make_uint2(pack_bf16(acc0.x, acc0.y), pack_bf16(acc0.z, acc0.w));
    if (r0 + 1 < N) y2[(size_t)(r0 + 1) * 16 + tx] =
        make_uint2(pack_bf16(acc1.x, acc1.y), pack_bf16(acc1.z, acc1.w));
    if (r0 + 2 < N) y2[(size_t)(r0 + 2) * 16 + tx] =
        make_uint2(pack_bf16(acc2.x, acc2.y), pack_bf16(acc2.z, acc2.w));
    if (r0 + 3 < N) y2[(size_t)(r0 + 3) * 16 + tx] =
        make_uint2(pack_bf16(acc3.x, acc3.y), pack_bf16(acc3.z, acc3.w));
}

// ============================================================================
// gather-sum aggregation over bf16 y (R9 64-lane/row variant — line-optimal:
// one 128B line per edge; at the measured ~3.66 TB/s gather plateau)
// ============================================================================

__global__ __launch_bounds__(256)
void agg_bf16_kernel(const uint4* __restrict__ y4, const int* __restrict__ offsets,
                     const int* __restrict__ sorted_src, const float* __restrict__ norm_dst,
                     float4* __restrict__ out4, int N) {
    int wave = (blockIdx.x << 2) + (threadIdx.x >> 6);
    if (wave >= N) return;
    int lane = threadIdx.x & 63;
    int g = lane >> 3;   // edge slot 0..7
    int q = lane & 7;    // feature-eighth 0..7
    int beg = offsets[wave];
    int end = offsets[wave + 1];
    float nd = norm_dst[wave];
    float a0 = 0.f, a1 = 0.f, a2 = 0.f, a3 = 0.f, a4 = 0.f, a5 = 0.f, a6 = 0.f, a7 = 0.f;
    int j = beg + g;
    while (j + 8 < end) {   // 2 edges per group per iter
        int s0 = sorted_src[j];
        int s1 = sorted_src[j + 8];
        uint4 v0 = y4[(size_t)s0 * 8 + q];
        uint4 v1 = y4[(size_t)s1 * 8 + q];
        a0 += blo(v0.x) + blo(v1.x); a1 += bhi(v0.x) + bhi(v1.x);
        a2 += blo(v0.y) + blo(v1.y); a3 += bhi(v0.y) + bhi(v1.y);
        a4 += blo(v0.z) + blo(v1.z); a5 += bhi(v0.z) + bhi(v1.z);
        a6 += blo(v0.w) + blo(v1.w); a7 += bhi(v0.w) + bhi(v1.w);
        j += 16;
    }
    if (j < end) {
        int s = sorted_src[j];
        uint4 v = y4[(size_t)s * 8 + q];
        a0 += blo(v.x); a1 += bhi(v.x);
        a2 += blo(v.y); a3 += bhi(v.y);
        a4 += blo(v.z); a5 += bhi(v.z);
        a6 += blo(v.w); a7 += bhi(v.w);
    }
    a0 += __shfl_xor(a0, 8);  a1 += __shfl_xor(a1, 8);
    a2 += __shfl_xor(a2, 8);  a3 += __shfl_xor(a3, 8);
    a4 += __shfl_xor(a4, 8);  a5 += __shfl_xor(a5, 8);
    a6 += __shfl_xor(a6, 8);  a7 += __shfl_xor(a7, 8);
    a0 += __shfl_xor(a0, 16); a1 += __shfl_xor(a1, 16);
    a2 += __shfl_xor(a2, 16); a3 += __shfl_xor(a3, 16);
    a4 += __shfl_xor(a4, 16); a5 += __shfl_xor(a5, 16);
    a6 += __shfl_xor(a6, 16); a7 += __shfl_xor(a7, 16);
    a0 += __shfl_xor(a0, 32); a1 += __shfl_xor(a1, 32);
    a2 += __shfl_xor(a2, 32); a3 += __shfl_xor(a3, 32);
    a4 += __shfl_xor(a4, 32); a5 += __shfl_xor(a5, 32);
    a6 += __shfl_xor(a6, 32); a7 += __shfl_xor(a7, 32);
    if (lane < 8) {
        float4 o1; o1.x = a0 * nd; o1.y = a1 * nd; o1.z = a2 * nd; o1.w = a3 * nd;
        float4 o2; o2.x = a4 * nd; o2.y = a5 * nd; o2.z = a6 * nd; o2.w = a7 * nd;
        out4[(size_t)wave * 16 + q * 2]     = o1;
        out4[(size_t)wave * 16 + q * 2 + 1] = o2;
    }
}

// ============================================================================
// FALLBACK kernels (rounds 3/4, proven)
// ============================================================================

__global__ void hist4_kernel(const int* __restrict__ src, const int* __restrict__ dst,
                             int* __restrict__ cnt, int E, int N, int S) {
    int i = blockIdx.x * blockDim.x + threadIdx.x;
    int E4 = E >> 2;
    if (i < E4) {
        int4 s = reinterpret_cast<const int4*>(src)[i];
        int4 d = reinterpret_cast<const int4*>(dst)[i];
        atomicAdd(&cnt[s.x * S], 1); atomicAdd(&cnt[s.y * S], 1);
        atomicAdd(&cnt[s.z * S], 1); atomicAdd(&cnt[s.w * S], 1);
        atomicAdd(&cnt[(N + d.x) * S], 1); atomicAdd(&cnt[(N + d.y) * S], 1);
        atomicAdd(&cnt[(N + d.z) * S], 1); atomicAdd(&cnt[(N + d.w) * S], 1);
    }
    if (i == 0) {
        for (int e = E4 << 2; e < E; ++e) {
            atomicAdd(&cnt[src[e] * S], 1);
            atomicAdd(&cnt[(N + dst[e]) * S], 1);
        }
    }
}

__global__ void norm_from_cnt_kernel(const int* __restrict__ cnt, float* __restrict__ norm,
                                     int twoN, int S) {
    int i = blockIdx.x * blockDim.x + threadIdx.x;
    if (i < twoN) {
        int c = cnt[(size_t)i * S];
        float v = (float)(c < 1 ? 1 : c);
        norm[i] = 1.0f / sqrtf(v);
    }
}

__global__ void bin4_kernel(const int* __restrict__ src, const int* __restrict__ dst,
                            int* __restrict__ cursor, int* __restrict__ sorted_src,
                            int E, int S) {
    int i = blockIdx.x * blockDim.x + threadIdx.x;
    int E4 = E >> 2;
    if (i < E4) {
        int4 s = reinterpret_cast<const int4*>(src)[i];
        int4 d = reinterpret_cast<const int4*>(dst)[i];
        sorted_src[atomicAdd(&cursor[d.x * S], 1)] = s.x;
        sorted_src[atomicAdd(&cursor[d.y * S], 1)] = s.y;
        sorted_src[atomicAdd(&cursor[d.z * S], 1)] = s.z;
        sorted_src[atomicAdd(&cursor[d.w * S], 1)] = s.w;
    }
    if (i == 0) {
        for (int e = E4 << 2; e < E; ++e) {
            sorted_src[atomicAdd(&cursor[dst[e] * S], 1)] = src[e];
        }
    }
}

__global__ void deg_kernel(const int* __restrict__ src, const int* __restrict__ dst,
                           float* __restrict__ deg, int E, int N) {
    int i = blockIdx.x * blockDim.x + threadIdx.x;
    if (i < E) {
        atomicAdd(&deg[src[i]], 1.0f);
        atomicAdd(&deg[N + dst[i]], 1.0f);
    }
}

__global__ void norm_kernel(float* __restrict__ deg, int twoN) {
    int i = blockIdx.x * blockDim.x + threadIdx.x;
    if (i < twoN) {
        float v = deg[i];
        v = v < 1.0f ? 1.0f : v;
        deg[i] = 1.0f / sqrtf(v);
    }
}

__global__ void scatter_kernel(const float* __restrict__ x, const int* __restrict__ src,
                               const int* __restrict__ dst, const float* __restrict__ norm_src,
                               float* __restrict__ agg, int E) {
    int tid = blockIdx.x * blockDim.x + threadIdx.x;
    int e = tid >> 4;
    int q = tid & 15;
    if (e < E) {
        int s = src[e];
        int d = dst[e];
        float ns = norm_src[s];
        float4 v = reinterpret_cast<const float4*>(x)[s * (D / 4) + q];
        float* o = agg + (long long)d * D + q * 4;
        atomicAdd(o + 0, v.x * ns);
        atomicAdd(o + 1, v.y * ns);
        atomicAdd(o + 2, v.z * ns);
        atomicAdd(o + 3, v.w * ns);
    }
}

__global__ __launch_bounds__(256) void gemm_kernel(float* __restrict__ out,
                                                   const float* __restrict__ W,
                                                   const float* __restrict__ norm_dst,
                                                   int N, int rows_per_block) {
    __shared__ float Ws[D * D];
    __shared__ float rowS[4][D];
    for (int i = threadIdx.x; i < D * D; i += 256) Ws[i] = W[i];

    int f   = threadIdx.x & 63;
    int sub = threadIdx.x >> 6;
    int base = blockIdx.x * rows_per_block;

    for (int r0 = 0; r0 < rows_per_block; r0 += 4) {
        int r = base + r0 + sub;
        bool valid = (r < N);
        __syncthreads();
        if (valid) rowS[sub][f] = out[(long long)r * D + f] * norm_dst[r];
        __syncthreads();
        if (valid) {
            float acc = 0.0f;
            #pragma unroll
            for (int k = 0; k < D; ++k) acc += rowS[sub][k] * Ws[k * D + f];
            out[(long long)r * D + f] = acc;
        }
    }
}

// ============================================================================
extern "C" void kernel_launch(void* const* d_in, const int* in_sizes, int n_in,
                              void* d_out, int out_size, void* d_ws, size_t ws_size,
                              hipStream_t stream) {
    const float* x   = (const float*)d_in[0];
    const float* W   = (const float*)d_in[1];
    const int*   src = (const int*)d_in[2];
    const int*   dst = (const int*)d_in[3];

    const int N = in_sizes[0] / D;   // 100000
    const int E = in_sizes[2];       // 1600000
    const int nblk = (N + SCAN_TILE - 1) / SCAN_TILE;
    const int NBv = (N + BW - 1) >> BSHIFT;
    const int nChunks = (E + CHUNK - 1) / CHUNK;

    // ---- fast-path workspace layout (4-byte words)
    size_t w_norm = 0;                                    // 2N floats (norm_src | norm_dst)
    size_t w_offs = w_norm + 2 * (size_t)N;               // N+1 ints
    size_t w_bcd  = w_offs + (size_t)N + 1;               // nChunks*NBv
    size_t w_bsd  = w_bcd + (size_t)nChunks * NBv;        // nChunks*NBv
    size_t w_bcs  = w_bsd + (size_t)nChunks * NBv;        // nChunks*NBv
    size_t w_bss  = w_bcs + (size_t)nChunks * NBv;        // nChunks*NBv
    size_t w_btd  = w_bss + (size_t)nChunks * NBv;        // NBv
    size_t w_bbd  = w_btd + (size_t)NBv;                  // NBv+1
    size_t w_bts  = w_bbd + (size_t)NBv + 1;              // NBv
    size_t w_bbs  = w_bts + (size_t)NBv;                  // NBv+1
    size_t w_bkd  = w_bbs + (size_t)NBv + 1;              // E uints (dst-bucketed packed)
    size_t w_bks  = w_bkd + (size_t)E;                    // (E+1)/2 words (src-bucketed u16)
    size_t w_sort = w_bks + ((size_t)E + 1) / 2;          // E ints
    size_t w_y    = (w_sort + (size_t)E + 3) & ~(size_t)3;  // N*32 words (bf16 y), 16B align
    size_t need_new = (w_y + (size_t)N * 32) * 4;

    bool new_ok = (N <= (1 << 17)) && (NBv <= 256) && (ws_size >= need_new);

    if (new_ok) {
        float*          norm       = (float*)d_ws + w_norm;
        int*            offsets    = (int*)d_ws + w_offs;
        int*            bcnt_d     = (int*)d_ws + w_bcd;
        int*            bstart_d   = (int*)d_ws + w_bsd;
        int*            bcnt_s     = (int*)d_ws + w_bcs;
        int*            bstart_s   = (int*)d_ws + w_bss;
        int*            btot_d     = (int*)d_ws + w_btd;
        int*            bbeg_d     = (int*)d_ws + w_bbd;
        int*            btot_s     = (int*)d_ws + w_bts;
        int*            bbeg_s     = (int*)d_ws + w_bbs;
        unsigned*       bucketed_d = (unsigned*)d_ws + w_bkd;
        unsigned short* bucketed_s = (unsigned short*)((int*)d_ws + w_bks);
        int*            sorted_src = (int*)d_ws + w_sort;
        unsigned*       y          = (unsigned*)d_ws + w_y;
        float*          out        = (float*)d_out;
        float*          norm_dst_p = norm + N;

        // --- try single cooperative prologue (5 launches -> 1)
        bool coop_done = false;
        int coop = 0, dev = 0;
        if (hipGetDevice(&dev) == hipSuccess &&
            hipDeviceGetAttribute(&coop, hipDeviceAttributeCooperativeLaunch, dev)
                == hipSuccess && coop) {
            int N_ = N, E_ = E, NBv_ = NBv, nChunks_ = nChunks;
            void* args[] = {
                (void*)&src, (void*)&dst,
                (void*)&bcnt_d, (void*)&bcnt_s,
                (void*)&bstart_d, (void*)&bstart_s,
                (void*)&btot_d, (void*)&btot_s,
                (void*)&bbeg_d, (void*)&bbeg_s,
                (void*)&bucketed_d, (void*)&bucketed_s,
                (void*)&offsets, (void*)&norm_dst_p, (void*)&norm, (void*)&sorted_src,
                (void*)&N_, (void*)&E_, (void*)&NBv_, (void*)&nChunks_};
            hipError_t err = hipLaunchCooperativeKernel(
                reinterpret_cast<void*>(csr_build_coop_kernel),
                dim3(2 * NBv), dim3(256), args, 0, stream);
            coop_done = (err == hipSuccess);
        }

        if (!coop_done) {
            bucket_count_chunks2_kernel<<<nChunks, 256, 0, stream>>>(src, dst, bcnt_d,
                                                                     bcnt_s, E, NBv);
            bucket_scan_chunks2_kernel<<<2 * NBv, 256, 0, stream>>>(bcnt_d, bstart_d, btot_d,
                                                                    bcnt_s, bstart_s, btot_s,
                                                                    nChunks, NBv);
            bucket_base2_kernel<<<2, 256, 0, stream>>>(btot_d, bbeg_d, btot_s, bbeg_s,
                                                       NBv, E);
            bucket_scatter2_kernel<<<nChunks, 256, 0, stream>>>(src, dst, bstart_d, bbeg_d,
                                                                bstart_s, bbeg_s, bucketed_d,
                                                                bucketed_s, E, NBv);
            bucket_finalize_kernel<<<2 * NBv, 256, 0, stream>>>(bucketed_d, bbeg_d,
                                                                bucketed_s, bbeg_s,
                                                                offsets, norm + N, norm,
                                                                sorted_src, N, E, NBv);
        }

        xw_tiled_kernel<<<(N + XW_ROWS - 1) / XW_ROWS, 256, 0, stream>>>(
            (const float4*)x, W, norm, y, N);
        int agg_blocks = (N + 3) / 4;   // one wave per row
        agg_bf16_kernel<<<agg_blocks, 256, 0, stream>>>(
            (const uint4*)y, offsets, sorted_src, norm + N, (float4*)out, N);
        return;
    }

    // ---- FALLBACK path A (atomic-cursor CSR + bf16 xw/agg)
    {
        const int strides[4] = {16, 8, 4, 1};
        int S = 0;
        size_t o_norm = 0, o_cnt = 0, o_offs = 0, o_cur = 0, o_part = 0, o_sort = 0, o_yy = 0;
        size_t need_A = 0;
        for (int t = 0; t < 4; ++t) {
            int s = strides[t];
            o_norm = 0;
            o_cnt  = o_norm + 2 * (size_t)N;
            o_offs = o_cnt + 2 * (size_t)N * s;
            o_cur  = o_offs + (size_t)N + 1;
            o_part = o_cur + (size_t)N * s;
            o_sort = o_part + SCAN_THREADS;
            o_yy   = (o_sort + (size_t)E + 3) & ~(size_t)3;
            need_A = (o_yy + (size_t)N * 32) * 4;
            if (ws_size >= need_A) { S = s; break; }
        }
        if (S > 0 && nblk <= SCAN_THREADS) {
            float*    norm       = (float*)d_ws + o_norm;
            int*      cnt        = (int*)d_ws + o_cnt;
            int*      offsets    = (int*)d_ws + o_offs;
            int*      cursor     = (int*)d_ws + o_cur;
            int*      partials   = (int*)d_ws + o_part;
            int*      sorted_src = (int*)d_ws + o_sort;
            unsigned* y          = (unsigned*)d_ws + o_yy;
            float*    out        = (float*)d_out;

            hipMemsetAsync(cnt, 0, 2 * (size_t)N * S * sizeof(int), stream);

            int E4 = E >> 2;
            int histblk = (E4 + 255) / 256; if (histblk < 1) histblk = 1;
            hist4_kernel<<<histblk, 256, 0, stream>>>(src, dst, cnt, E, N, S);
            norm_from_cnt_kernel<<<(2 * N + 255) / 256, 256, 0, stream>>>(cnt, norm, 2 * N, S);
            scan_blocks_kernel<<<nblk, SCAN_THREADS, 0, stream>>>(cnt + (size_t)N * S, offsets,
                                                                  partials, N, S);
            scan_partials_kernel<<<1, SCAN_THREADS, 0, stream>>>(partials, nblk);
            add_back_kernel<<<(N + 255) / 256, 256, 0, stream>>>(offsets, cursor, partials,
                                                                 N, E, S);
            bin4_kernel<<<histblk, 256, 0, stream>>>(src, dst, cursor, sorted_src, E, S);

            xw_tiled_kernel<<<(N + XW_ROWS - 1) / XW_ROWS, 256, 0, stream>>>(
                (const float4*)x, W, norm, y, N);
            int agg_blocks = (N + 3) / 4;
            agg_bf16_kernel<<<agg_blocks, 256, 0, stream>>>(
                (const uint4*)y, offsets, sorted_src, norm + N, (float4*)out, N);
            return;
        }
    }

    // ---- LAST-RESORT fallback (round 0): float-atomic scatter
    {
        float* deg = (float*)d_ws;
        float* agg = (float*)d_out;

        hipMemsetAsync(deg, 0, (size_t)2 * N * sizeof(float), stream);
        hipMemsetAsync(agg, 0, (size_t)N * D * sizeof(float), stream);

        deg_kernel<<<(E + 255) / 256, 256, 0, stream>>>(src, dst, deg, E, N);
        norm_kernel<<<(2 * N + 255) / 256, 256, 0, stream>>>(deg, 2 * N);

        long long scatter_threads = (long long)E * 16;
        int scatter_blocks = (int)((scatter_threads + 255) / 256);
        scatter_kernel<<<scatter_blocks, 256, 0, stream>>>(x, src, dst, deg, agg, E);

        const int rows_per_block = 64;
        int gemm_blocks = (N + rows_per_block - 1) / rows_per_block;
        gemm_kernel<<<gemm_blocks, 256, 0, stream>>>(agg, W, deg + N, N, rows_per_block);
    }
}

// Round 15
// 125.929 us; speedup vs baseline: 3.5293x; 3.5293x over previous
//
#include <hip/hip_runtime.h>
#include <math.h>

#define D 64
#define SCAN_TILE 1024
#define SCAN_THREADS 256
#define SCAN_ITEMS 4
#define HS 16          // hist padding stride (fallback path only)
#define BSHIFT 9       // bucket = id >> 9 (512 nodes per bucket)
#define BW 512
#define CHUNK 4096     // edges per bucketing block (R13-tuned)

// ---------------------------------------------------------------------------
// bf16 helpers (packed 2 x bf16 per uint; RNE rounding)
// ---------------------------------------------------------------------------
__device__ __forceinline__ unsigned pack_bf16(float a, float b) {
    unsigned ua = __float_as_uint(a);
    unsigned ub = __float_as_uint(b);
    ua = (ua + 0x7fffu + ((ua >> 16) & 1u)) >> 16;
    ub = (ub + 0x7fffu + ((ub >> 16) & 1u)) >> 16;
    return ua | (ub << 16);
}
__device__ __forceinline__ float blo(unsigned u) { return __uint_as_float(u << 16); }
__device__ __forceinline__ float bhi(unsigned u) { return __uint_as_float(u & 0xffff0000u); }

// ============================================================================
// FAST PATH: dual-key LDS bucketing (no global random atomics anywhere)
// R15: int4-vectorized index reads in count/scatter (R14 coop grid.sync was
// 5x WORSE than launch boundaries on gfx950 — reverted to 5-launch form).
// ============================================================================

// --- Pass A: per-chunk bucket counts for BOTH dst and src (LDS only, int4)
__global__ __launch_bounds__(256)
void bucket_count_chunks2_kernel(const int* __restrict__ src, const int* __restrict__ dst,
                                 int* __restrict__ bcnt_d, int* __restrict__ bcnt_s,
                                 int E, int NBv) {
    __shared__ int cd[256];
    __shared__ int cs[256];
    for (int i = threadIdx.x; i < NBv; i += 256) { cd[i] = 0; cs[i] = 0; }
    __syncthreads();
    int beg = blockIdx.x * CHUNK;
    int end = beg + CHUNK; if (end > E) end = E;
    int n4 = (end - beg) >> 2;
    const int4* s4 = reinterpret_cast<const int4*>(src + beg);
    const int4* d4 = reinterpret_cast<const int4*>(dst + beg);
    for (int j = threadIdx.x; j < n4; j += 256) {
        int4 dv = d4[j];
        int4 sv = s4[j];
        atomicAdd(&cd[dv.x >> BSHIFT], 1);
        atomicAdd(&cd[dv.y >> BSHIFT], 1);
        atomicAdd(&cd[dv.z >> BSHIFT], 1);
        atomicAdd(&cd[dv.w >> BSHIFT], 1);
        atomicAdd(&cs[sv.x >> BSHIFT], 1);
        atomicAdd(&cs[sv.y >> BSHIFT], 1);
        atomicAdd(&cs[sv.z >> BSHIFT], 1);
        atomicAdd(&cs[sv.w >> BSHIFT], 1);
    }
    for (int j = beg + (n4 << 2) + threadIdx.x; j < end; j += 256) {
        atomicAdd(&cd[dst[j] >> BSHIFT], 1);
        atomicAdd(&cs[src[j] >> BSHIFT], 1);
    }
    __syncthreads();
    for (int i = threadIdx.x; i < NBv; i += 256) {
        bcnt_d[(size_t)blockIdx.x * NBv + i] = cd[i];
        bcnt_s[(size_t)blockIdx.x * NBv + i] = cs[i];
    }
}

// --- Pass B1: per-bucket parallel scan over the chunk axis (dst & src in one grid)
__global__ __launch_bounds__(256)
void bucket_scan_chunks2_kernel(const int* __restrict__ bcnt_d, int* __restrict__ bstart_d,
                                int* __restrict__ btot_d,
                                const int* __restrict__ bcnt_s, int* __restrict__ bstart_s,
                                int* __restrict__ btot_s,
                                int nChunks, int NBv) {
    __shared__ int sdata[256];
    int which = (blockIdx.x >= NBv) ? 1 : 0;
    int b = blockIdx.x - which * NBv;
    const int* bcnt   = which ? bcnt_s : bcnt_d;
    int*       bstart = which ? bstart_s : bstart_d;
    int*       btot   = which ? btot_s : btot_d;
    int t = threadIdx.x;
    int carry = 0;
    for (int c0 = 0; c0 < nChunks; c0 += 256) {
        int c = c0 + t;
        int v = (c < nChunks) ? bcnt[(size_t)c * NBv + b] : 0;
        sdata[t] = v;
        __syncthreads();
        for (int off = 1; off < 256; off <<= 1) {
            int val = (t >= off) ? sdata[t - off] : 0;
            __syncthreads();
            if (t >= off) sdata[t] += val;
            __syncthreads();
        }
        if (c < nChunks) bstart[(size_t)c * NBv + b] = carry + sdata[t] - v;
        carry += sdata[255];
        __syncthreads();
    }
    if (t == 0) btot[b] = carry;
}

// --- Pass B2: exclusive scan of both btot arrays -> bucket bases (2 blocks)
__global__ __launch_bounds__(256)
void bucket_base2_kernel(const int* __restrict__ btot_d, int* __restrict__ bbeg_d,
                         const int* __restrict__ btot_s, int* __restrict__ bbeg_s,
                         int NBv, int E) {
    __shared__ int sdata[256];
    const int* btot = (blockIdx.x == 0) ? btot_d : btot_s;
    int*       bbeg = (blockIdx.x == 0) ? bbeg_d : bbeg_s;
    int t = threadIdx.x;
    int v = (t < NBv) ? btot[t] : 0;
    sdata[t] = v;
    __syncthreads();
    for (int off = 1; off < 256; off <<= 1) {
        int val = (t >= off) ? sdata[t - off] : 0;
        __syncthreads();
        if (t >= off) sdata[t] += val;
        __syncthreads();
    }
    if (t < NBv) bbeg[t] = sdata[t] - v;
    if (t == 0) bbeg[NBv] = E;
}

// --- Pass C: scatter edges into dst-bucket runs (packed) AND src-bucket u16
//     stream (int4 index reads)
__global__ __launch_bounds__(256)
void bucket_scatter2_kernel(const int* __restrict__ src, const int* __restrict__ dst,
                            const int* __restrict__ bstart_d, const int* __restrict__ bbeg_d,
                            const int* __restrict__ bstart_s, const int* __restrict__ bbeg_s,
                            unsigned* __restrict__ bucketed_d,
                            unsigned short* __restrict__ bucketed_s,
                            int E, int NBv) {
    __shared__ int cur_d[256];
    __shared__ int cur_s[256];
    for (int i = threadIdx.x; i < NBv; i += 256) {
        cur_d[i] = bstart_d[(size_t)blockIdx.x * NBv + i] + bbeg_d[i];
        cur_s[i] = bstart_s[(size_t)blockIdx.x * NBv + i] + bbeg_s[i];
    }
    __syncthreads();
    int beg = blockIdx.x * CHUNK;
    int end = beg + CHUNK; if (end > E) end = E;
    int n4 = (end - beg) >> 2;
    const int4* s4 = reinterpret_cast<const int4*>(src + beg);
    const int4* d4 = reinterpret_cast<const int4*>(dst + beg);
    for (int j = threadIdx.x; j < n4; j += 256) {
        int4 dv = d4[j];
        int4 sv = s4[j];
        int pd, ps;
        pd = atomicAdd(&cur_d[dv.x >> BSHIFT], 1);
        bucketed_d[pd] = ((unsigned)(dv.x & (BW - 1)) << 17) | (unsigned)sv.x;
        pd = atomicAdd(&cur_d[dv.y >> BSHIFT], 1);
        bucketed_d[pd] = ((unsigned)(dv.y & (BW - 1)) << 17) | (unsigned)sv.y;
        pd = atomicAdd(&cur_d[dv.z >> BSHIFT], 1);
        bucketed_d[pd] = ((unsigned)(dv.z & (BW - 1)) << 17) | (unsigned)sv.z;
        pd = atomicAdd(&cur_d[dv.w >> BSHIFT], 1);
        bucketed_d[pd] = ((unsigned)(dv.w & (BW - 1)) << 17) | (unsigned)sv.w;
        ps = atomicAdd(&cur_s[sv.x >> BSHIFT], 1);
        bucketed_s[ps] = (unsigned short)(sv.x & (BW - 1));
        ps = atomicAdd(&cur_s[sv.y >> BSHIFT], 1);
        bucketed_s[ps] = (unsigned short)(sv.y & (BW - 1));
        ps = atomicAdd(&cur_s[sv.z >> BSHIFT], 1);
        bucketed_s[ps] = (unsigned short)(sv.z & (BW - 1));
        ps = atomicAdd(&cur_s[sv.w >> BSHIFT], 1);
        bucketed_s[ps] = (unsigned short)(sv.w & (BW - 1));
    }
    for (int j = beg + (n4 << 2) + threadIdx.x; j < end; j += 256) {
        int d = dst[j];
        int s = src[j];
        int pd = atomicAdd(&cur_d[d >> BSHIFT], 1);
        bucketed_d[pd] = ((unsigned)(d & (BW - 1)) << 17) | (unsigned)s;
        int ps = atomicAdd(&cur_s[s >> BSHIFT], 1);
        bucketed_s[ps] = (unsigned short)(s & (BW - 1));
    }
}

// --- Pass D (fused finalize): dst blocks: count -> 512-wide LDS scan ->
//     global CSR offsets + norm_dst + placement. src blocks: count -> norm_src.
__global__ __launch_bounds__(256)
void bucket_finalize_kernel(const unsigned* __restrict__ bucketed_d,
                            const int* __restrict__ bbeg_d,
                            const unsigned short* __restrict__ bucketed_s,
                            const int* __restrict__ bbeg_s,
                            int* __restrict__ offsets, float* __restrict__ norm_dst,
                            float* __restrict__ norm_src, int* __restrict__ sorted_src,
                            int N, int E, int NBv) {
    __shared__ int cnt[BW];
    __shared__ int cur[BW];
    __shared__ int ssum[256];
    int t = threadIdx.x;
    if (blockIdx.x < NBv) {
        int b = blockIdx.x;
        cnt[t] = 0; cnt[t + 256] = 0;
        __syncthreads();
        int beg = bbeg_d[b], end = bbeg_d[b + 1];
        for (int j = beg + t; j < end; j += 256)
            atomicAdd(&cnt[bucketed_d[j] >> 17], 1);
        __syncthreads();
        int c0 = cnt[2 * t], c1 = cnt[2 * t + 1];
        ssum[t] = c0 + c1;
        __syncthreads();
        for (int off = 1; off < 256; off <<= 1) {
            int v = (t >= off) ? ssum[t - off] : 0;
            __syncthreads();
            if (t >= off) ssum[t] += v;
            __syncthreads();
        }
        int excl = ssum[t] - (c0 + c1);
        int off0 = beg + excl;
        int off1 = off0 + c0;
        int dbase = b << BSHIFT;
        int d0 = dbase + 2 * t, d1 = dbase + 2 * t + 1;
        cur[2 * t] = off0; cur[2 * t + 1] = off1;
        if (d0 < N) {
            offsets[d0] = off0;
            norm_dst[d0] = 1.0f / sqrtf((float)(c0 < 1 ? 1 : c0));
        }
        if (d1 < N) {
            offsets[d1] = off1;
            norm_dst[d1] = 1.0f / sqrtf((float)(c1 < 1 ? 1 : c1));
        }
        if (b == NBv - 1 && t == 0) offsets[N] = E;
        __syncthreads();
        for (int j = beg + t; j < end; j += 256) {
            unsigned v = bucketed_d[j];
            int pos = atomicAdd(&cur[v >> 17], 1);
            sorted_src[pos] = (int)(v & 0x1FFFFu);
        }
    } else {
        int b = blockIdx.x - NBv;
        cnt[t] = 0; cnt[t + 256] = 0;
        __syncthreads();
        int beg = bbeg_s[b], end = bbeg_s[b + 1];
        for (int j = beg + t; j < end; j += 256)
            atomicAdd(&cnt[bucketed_s[j]], 1);
        __syncthreads();
        int sbase = b << BSHIFT;
        for (int i = t; i < BW; i += 256) {
            int s = sbase + i;
            if (s < N) {
                int c = cnt[i];
                norm_src[s] = 1.0f / sqrtf((float)(c < 1 ? 1 : c));
            }
        }
    }
}

// ============================================================================
// Scans (fallback path only)
// ============================================================================

__global__ __launch_bounds__(SCAN_THREADS)
void scan_blocks_kernel(const int* __restrict__ cnt_dst, int* __restrict__ offsets,
                        int* __restrict__ partials, int N, int S) {
    __shared__ int sdata[SCAN_THREADS];
    int t = threadIdx.x;
    int base = blockIdx.x * SCAN_TILE + t * SCAN_ITEMS;
    int v[SCAN_ITEMS];
    int sum = 0;
    #pragma unroll
    for (int i = 0; i < SCAN_ITEMS; ++i) {
        int idx = base + i;
        v[i] = (idx < N) ? cnt_dst[(size_t)idx * S] : 0;
        sum += v[i];
    }
    sdata[t] = sum;
    __syncthreads();
    for (int off = 1; off < SCAN_THREADS; off <<= 1) {
        int val = (t >= off) ? sdata[t - off] : 0;
        __syncthreads();
        if (t >= off) sdata[t] += val;
        __syncthreads();
    }
    int excl = sdata[t] - sum;
    if (t == SCAN_THREADS - 1) partials[blockIdx.x] = sdata[t];
    int run = excl;
    #pragma unroll
    for (int i = 0; i < SCAN_ITEMS; ++i) {
        int idx = base + i;
        if (idx < N) offsets[idx] = run;
        run += v[i];
    }
}

__global__ __launch_bounds__(SCAN_THREADS)
void scan_partials_kernel(int* __restrict__ partials, int nblk) {
    __shared__ int sdata[SCAN_THREADS];
    int t = threadIdx.x;
    int v = (t < nblk) ? partials[t] : 0;
    sdata[t] = v;
    __syncthreads();
    for (int off = 1; off < SCAN_THREADS; off <<= 1) {
        int val = (t >= off) ? sdata[t - off] : 0;
        __syncthreads();
        if (t >= off) sdata[t] += val;
        __syncthreads();
    }
    if (t < nblk) partials[t] = sdata[t] - v;
}

__global__ void add_back_kernel(int* __restrict__ offsets, int* __restrict__ cursor,
                                const int* __restrict__ partials, int N, int E, int S) {
    int i = blockIdx.x * blockDim.x + threadIdx.x;
    if (i < N) {
        int o = offsets[i] + partials[i >> 10];
        offsets[i] = o;
        cursor[(size_t)i * S] = o;
    }
    if (i == 0) offsets[N] = E;
}

// ============================================================================
// y = (x*norm_src)@W  (bf16-packed y) — register-tiled GEMM (R9 occupancy-fixed)
// ============================================================================

#define XW_ROWS 64
#define ATP 68   // padded row stride (floats)

__global__ __launch_bounds__(256, 4)
void xw_tiled_kernel(const float4* __restrict__ x4, const float* __restrict__ W,
                     const float* __restrict__ norm_src, unsigned* __restrict__ y, int N) {
    __shared__ float Ws[D * D];       // W[k][f], row-major
    __shared__ float At[D][ATP];      // At[k][local row]
    int t = threadIdx.x;

    for (int i = t; i < D * D / 4; i += 256)
        reinterpret_cast<float4*>(Ws)[i] = reinterpret_cast<const float4*>(W)[i];

    int rowbase = blockIdx.x * XW_ROWS;
    int lr = t >> 2;
    int qc = t & 3;
    int gr = rowbase + lr;
    float ns = (gr < N) ? norm_src[gr] : 0.0f;
    #pragma unroll
    for (int c = qc; c < 16; c += 4) {
        float4 v = (gr < N) ? x4[(size_t)gr * 16 + c] : make_float4(0.f, 0.f, 0.f, 0.f);
        At[c * 4 + 0][lr] = v.x * ns;
        At[c * 4 + 1][lr] = v.y * ns;
        At[c * 4 + 2][lr] = v.z * ns;
        At[c * 4 + 3][lr] = v.w * ns;
    }
    __syncthreads();

    int tx = t & 15;
    int ty = t >> 4;
    float4 acc0 = make_float4(0.f, 0.f, 0.f, 0.f);
    float4 acc1 = acc0, acc2 = acc0, acc3 = acc0;
    #pragma unroll 4
    for (int k = 0; k < D; ++k) {
        float4 a = *reinterpret_cast<const float4*>(&At[k][ty * 4]);
        float4 w = *reinterpret_cast<const float4*>(&Ws[k * D + tx * 4]);
        acc0.x += a.x * w.x; acc0.y += a.x * w.y; acc0.z += a.x * w.z; acc0.w += a.x * w.w;
        acc1.x += a.y * w.x; acc1.y += a.y * w.y; acc1.z += a.y * w.z; acc1.w += a.y * w.w;
        acc2.x += a.z * w.x; acc2.y += a.z * w.y; acc2.z += a.z * w.z; acc2.w += a.z * w.w;
        acc3.x += a.w * w.x; acc3.y += a.w * w.y; acc3.z += a.w * w.z; acc3.w += a.w * w.w;
    }

    uint2* y2 = reinterpret_cast<uint2*>(y);
    int r0 = rowbase + ty * 4;
    if (r0 + 0 < N) y2[(size_t)(r0 + 0) * 16 + tx] =
        make_uint2(pack_bf16(acc0.x, acc0.y), pack_bf16(acc0.z, acc0.w));
    if (r0 + 1 < N) y2[(size_t)(r0 + 1) * 16 + tx] =
        make_uint2(pack_bf16(acc1.x, acc1.y), pack_bf16(acc1.z, acc1.w));
    if (r0 + 2 < N) y2[(size_t)(r0 + 2) * 16 + tx] =
        make_uint2(pack_bf16(acc2.x, acc2.y), pack_bf16(acc2.z, acc2.w));
    if (r0 + 3 < N) y2[(size_t)(r0 + 3) * 16 + tx] =
        make_uint2(pack_bf16(acc3.x, acc3.y), pack_bf16(acc3.z, acc3.w));
}

// ============================================================================
// gather-sum aggregation over bf16 y (R9 64-lane/row variant — line-optimal:
// one 128B line per edge; at the measured ~3.66 TB/s gather plateau)
// ============================================================================

__global__ __launch_bounds__(256)
void agg_bf16_kernel(const uint4* __restrict__ y4, const int* __restrict__ offsets,
                     const int* __restrict__ sorted_src, const float* __restrict__ norm_dst,
                     float4* __restrict__ out4, int N) {
    int wave = (blockIdx.x << 2) + (threadIdx.x >> 6);
    if (wave >= N) return;
    int lane = threadIdx.x & 63;
    int g = lane >> 3;   // edge slot 0..7
    int q = lane & 7;    // feature-eighth 0..7
    int beg = offsets[wave];
    int end = offsets[wave + 1];
    float nd = norm_dst[wave];
    float a0 = 0.f, a1 = 0.f, a2 = 0.f, a3 = 0.f, a4 = 0.f, a5 = 0.f, a6 = 0.f, a7 = 0.f;
    int j = beg + g;
    while (j + 8 < end) {   // 2 edges per group per iter
        int s0 = sorted_src[j];
        int s1 = sorted_src[j + 8];
        uint4 v0 = y4[(size_t)s0 * 8 + q];
        uint4 v1 = y4[(size_t)s1 * 8 + q];
        a0 += blo(v0.x) + blo(v1.x); a1 += bhi(v0.x) + bhi(v1.x);
        a2 += blo(v0.y) + blo(v1.y); a3 += bhi(v0.y) + bhi(v1.y);
        a4 += blo(v0.z) + blo(v1.z); a5 += bhi(v0.z) + bhi(v1.z);
        a6 += blo(v0.w) + blo(v1.w); a7 += bhi(v0.w) + bhi(v1.w);
        j += 16;
    }
    if (j < end) {
        int s = sorted_src[j];
        uint4 v = y4[(size_t)s * 8 + q];
        a0 += blo(v.x); a1 += bhi(v.x);
        a2 += blo(v.y); a3 += bhi(v.y);
        a4 += blo(v.z); a5 += bhi(v.z);
        a6 += blo(v.w); a7 += bhi(v.w);
    }
    a0 += __shfl_xor(a0, 8);  a1 += __shfl_xor(a1, 8);
    a2 += __shfl_xor(a2, 8);  a3 += __shfl_xor(a3, 8);
    a4 += __shfl_xor(a4, 8);  a5 += __shfl_xor(a5, 8);
    a6 += __shfl_xor(a6, 8);  a7 += __shfl_xor(a7, 8);
    a0 += __shfl_xor(a0, 16); a1 += __shfl_xor(a1, 16);
    a2 += __shfl_xor(a2, 16); a3 += __shfl_xor(a3, 16);
    a4 += __shfl_xor(a4, 16); a5 += __shfl_xor(a5, 16);
    a6 += __shfl_xor(a6, 16); a7 += __shfl_xor(a7, 16);
    a0 += __shfl_xor(a0, 32); a1 += __shfl_xor(a1, 32);
    a2 += __shfl_xor(a2, 32); a3 += __shfl_xor(a3, 32);
    a4 += __shfl_xor(a4, 32); a5 += __shfl_xor(a5, 32);
    a6 += __shfl_xor(a6, 32); a7 += __shfl_xor(a7, 32);
    if (lane < 8) {
        float4 o1; o1.x = a0 * nd; o1.y = a1 * nd; o1.z = a2 * nd; o1.w = a3 * nd;
        float4 o2; o2.x = a4 * nd; o2.y = a5 * nd; o2.z = a6 * nd; o2.w = a7 * nd;
        out4[(size_t)wave * 16 + q * 2]     = o1;
        out4[(size_t)wave * 16 + q * 2 + 1] = o2;
    }
}

// ============================================================================
// FALLBACK kernels (rounds 3/4, proven)
// ============================================================================

__global__ void hist4_kernel(const int* __restrict__ src, const int* __restrict__ dst,
                             int* __restrict__ cnt, int E, int N, int S) {
    int i = blockIdx.x * blockDim.x + threadIdx.x;
    int E4 = E >> 2;
    if (i < E4) {
        int4 s = reinterpret_cast<const int4*>(src)[i];
        int4 d = reinterpret_cast<const int4*>(dst)[i];
        atomicAdd(&cnt[s.x * S], 1); atomicAdd(&cnt[s.y * S], 1);
        atomicAdd(&cnt[s.z * S], 1); atomicAdd(&cnt[s.w * S], 1);
        atomicAdd(&cnt[(N + d.x) * S], 1); atomicAdd(&cnt[(N + d.y) * S], 1);
        atomicAdd(&cnt[(N + d.z) * S], 1); atomicAdd(&cnt[(N + d.w) * S], 1);
    }
    if (i == 0) {
        for (int e = E4 << 2; e < E; ++e) {
            atomicAdd(&cnt[src[e] * S], 1);
            atomicAdd(&cnt[(N + dst[e]) * S], 1);
        }
    }
}

__global__ void norm_from_cnt_kernel(const int* __restrict__ cnt, float* __restrict__ norm,
                                     int twoN, int S) {
    int i = blockIdx.x * blockDim.x + threadIdx.x;
    if (i < twoN) {
        int c = cnt[(size_t)i * S];
        float v = (float)(c < 1 ? 1 : c);
        norm[i] = 1.0f / sqrtf(v);
    }
}

__global__ void bin4_kernel(const int* __restrict__ src, const int* __restrict__ dst,
                            int* __restrict__ cursor, int* __restrict__ sorted_src,
                            int E, int S) {
    int i = blockIdx.x * blockDim.x + threadIdx.x;
    int E4 = E >> 2;
    if (i < E4) {
        int4 s = reinterpret_cast<const int4*>(src)[i];
        int4 d = reinterpret_cast<const int4*>(dst)[i];
        sorted_src[atomicAdd(&cursor[d.x * S], 1)] = s.x;
        sorted_src[atomicAdd(&cursor[d.y * S], 1)] = s.y;
        sorted_src[atomicAdd(&cursor[d.z * S], 1)] = s.z;
        sorted_src[atomicAdd(&cursor[d.w * S], 1)] = s.w;
    }
    if (i == 0) {
        for (int e = E4 << 2; e < E; ++e) {
            sorted_src[atomicAdd(&cursor[dst[e] * S], 1)] = src[e];
        }
    }
}

__global__ void deg_kernel(const int* __restrict__ src, const int* __restrict__ dst,
                           float* __restrict__ deg, int E, int N) {
    int i = blockIdx.x * blockDim.x + threadIdx.x;
    if (i < E) {
        atomicAdd(&deg[src[i]], 1.0f);
        atomicAdd(&deg[N + dst[i]], 1.0f);
    }
}

__global__ void norm_kernel(float* __restrict__ deg, int twoN) {
    int i = blockIdx.x * blockDim.x + threadIdx.x;
    if (i < twoN) {
        float v = deg[i];
        v = v < 1.0f ? 1.0f : v;
        deg[i] = 1.0f / sqrtf(v);
    }
}

__global__ void scatter_kernel(const float* __restrict__ x, const int* __restrict__ src,
                               const int* __restrict__ dst, const float* __restrict__ norm_src,
                               float* __restrict__ agg, int E) {
    int tid = blockIdx.x * blockDim.x + threadIdx.x;
    int e = tid >> 4;
    int q = tid & 15;
    if (e < E) {
        int s = src[e];
        int d = dst[e];
        float ns = norm_src[s];
        float4 v = reinterpret_cast<const float4*>(x)[s * (D / 4) + q];
        float* o = agg + (long long)d * D + q * 4;
        atomicAdd(o + 0, v.x * ns);
        atomicAdd(o + 1, v.y * ns);
        atomicAdd(o + 2, v.z * ns);
        atomicAdd(o + 3, v.w * ns);
    }
}

__global__ __launch_bounds__(256) void gemm_kernel(float* __restrict__ out,
                                                   const float* __restrict__ W,
                                                   const float* __restrict__ norm_dst,
                                                   int N, int rows_per_block) {
    __shared__ float Ws[D * D];
    __shared__ float rowS[4][D];
    for (int i = threadIdx.x; i < D * D; i += 256) Ws[i] = W[i];

    int f   = threadIdx.x & 63;
    int sub = threadIdx.x >> 6;
    int base = blockIdx.x * rows_per_block;

    for (int r0 = 0; r0 < rows_per_block; r0 += 4) {
        int r = base + r0 + sub;
        bool valid = (r < N);
        __syncthreads();
        if (valid) rowS[sub][f] = out[(long long)r * D + f] * norm_dst[r];
        __syncthreads();
        if (valid) {
            float acc = 0.0f;
            #pragma unroll
            for (int k = 0; k < D; ++k) acc += rowS[sub][k] * Ws[k * D + f];
            out[(long long)r * D + f] = acc;
        }
    }
}

// ============================================================================
extern "C" void kernel_launch(void* const* d_in, const int* in_sizes, int n_in,
                              void* d_out, int out_size, void* d_ws, size_t ws_size,
                              hipStream_t stream) {
    const float* x   = (const float*)d_in[0];
    const float* W   = (const float*)d_in[1];
    const int*   src = (const int*)d_in[2];
    const int*   dst = (const int*)d_in[3];

    const int N = in_sizes[0] / D;   // 100000
    const int E = in_sizes[2];       // 1600000
    const int nblk = (N + SCAN_TILE - 1) / SCAN_TILE;
    const int NBv = (N + BW - 1) >> BSHIFT;
    const int nChunks = (E + CHUNK - 1) / CHUNK;

    // ---- fast-path workspace layout (4-byte words)
    size_t w_norm = 0;                                    // 2N floats (norm_src | norm_dst)
    size_t w_offs = w_norm + 2 * (size_t)N;               // N+1 ints
    size_t w_bcd  = w_offs + (size_t)N + 1;               // nChunks*NBv
    size_t w_bsd  = w_bcd + (size_t)nChunks * NBv;        // nChunks*NBv
    size_t w_bcs  = w_bsd + (size_t)nChunks * NBv;        // nChunks*NBv
    size_t w_bss  = w_bcs + (size_t)nChunks * NBv;        // nChunks*NBv
    size_t w_btd  = w_bss + (size_t)nChunks * NBv;        // NBv
    size_t w_bbd  = w_btd + (size_t)NBv;                  // NBv+1
    size_t w_bts  = w_bbd + (size_t)NBv + 1;              // NBv
    size_t w_bbs  = w_bts + (size_t)NBv;                  // NBv+1
    size_t w_bkd  = w_bbs + (size_t)NBv + 1;              // E uints (dst-bucketed packed)
    size_t w_bks  = w_bkd + (size_t)E;                    // (E+1)/2 words (src-bucketed u16)
    size_t w_sort = w_bks + ((size_t)E + 1) / 2;          // E ints
    size_t w_y    = (w_sort + (size_t)E + 3) & ~(size_t)3;  // N*32 words (bf16 y), 16B align
    size_t need_new = (w_y + (size_t)N * 32) * 4;

    bool new_ok = (N <= (1 << 17)) && (NBv <= 256) && (ws_size >= need_new);

    if (new_ok) {
        float*          norm       = (float*)d_ws + w_norm;
        int*            offsets    = (int*)d_ws + w_offs;
        int*            bcnt_d     = (int*)d_ws + w_bcd;
        int*            bstart_d   = (int*)d_ws + w_bsd;
        int*            bcnt_s     = (int*)d_ws + w_bcs;
        int*            bstart_s   = (int*)d_ws + w_bss;
        int*            btot_d     = (int*)d_ws + w_btd;
        int*            bbeg_d     = (int*)d_ws + w_bbd;
        int*            btot_s     = (int*)d_ws + w_bts;
        int*            bbeg_s     = (int*)d_ws + w_bbs;
        unsigned*       bucketed_d = (unsigned*)d_ws + w_bkd;
        unsigned short* bucketed_s = (unsigned short*)((int*)d_ws + w_bks);
        int*            sorted_src = (int*)d_ws + w_sort;
        unsigned*       y          = (unsigned*)d_ws + w_y;
        float*          out        = (float*)d_out;

        bucket_count_chunks2_kernel<<<nChunks, 256, 0, stream>>>(src, dst, bcnt_d, bcnt_s,
                                                                 E, NBv);
        bucket_scan_chunks2_kernel<<<2 * NBv, 256, 0, stream>>>(bcnt_d, bstart_d, btot_d,
                                                                bcnt_s, bstart_s, btot_s,
                                                                nChunks, NBv);
        bucket_base2_kernel<<<2, 256, 0, stream>>>(btot_d, bbeg_d, btot_s, bbeg_s, NBv, E);
        bucket_scatter2_kernel<<<nChunks, 256, 0, stream>>>(src, dst, bstart_d, bbeg_d,
                                                            bstart_s, bbeg_s, bucketed_d,
                                                            bucketed_s, E, NBv);
        bucket_finalize_kernel<<<2 * NBv, 256, 0, stream>>>(bucketed_d, bbeg_d,
                                                            bucketed_s, bbeg_s,
                                                            offsets, norm + N, norm,
                                                            sorted_src, N, E, NBv);

        xw_tiled_kernel<<<(N + XW_ROWS - 1) / XW_ROWS, 256, 0, stream>>>(
            (const float4*)x, W, norm, y, N);
        int agg_blocks = (N + 3) / 4;   // one wave per row
        agg_bf16_kernel<<<agg_blocks, 256, 0, stream>>>(
            (const uint4*)y, offsets, sorted_src, norm + N, (float4*)out, N);
        return;
    }

    // ---- FALLBACK path A (atomic-cursor CSR + bf16 xw/agg)
    {
        const int strides[4] = {16, 8, 4, 1};
        int S = 0;
        size_t o_norm = 0, o_cnt = 0, o_offs = 0, o_cur = 0, o_part = 0, o_sort = 0, o_yy = 0;
        size_t need_A = 0;
        for (int t = 0; t < 4; ++t) {
            int s = strides[t];
            o_norm = 0;
            o_cnt  = o_norm + 2 * (size_t)N;
            o_offs = o_cnt + 2 * (size_t)N * s;
            o_cur  = o_offs + (size_t)N + 1;
            o_part = o_cur + (size_t)N * s;
            o_sort = o_part + SCAN_THREADS;
            o_yy   = (o_sort + (size_t)E + 3) & ~(size_t)3;
            need_A = (o_yy + (size_t)N * 32) * 4;
            if (ws_size >= need_A) { S = s; break; }
        }
        if (S > 0 && nblk <= SCAN_THREADS) {
            float*    norm       = (float*)d_ws + o_norm;
            int*      cnt        = (int*)d_ws + o_cnt;
            int*      offsets    = (int*)d_ws + o_offs;
            int*      cursor     = (int*)d_ws + o_cur;
            int*      partials   = (int*)d_ws + o_part;
            int*      sorted_src = (int*)d_ws + o_sort;
            unsigned* y          = (unsigned*)d_ws + o_yy;
            float*    out        = (float*)d_out;

            hipMemsetAsync(cnt, 0, 2 * (size_t)N * S * sizeof(int), stream);

            int E4 = E >> 2;
            int histblk = (E4 + 255) / 256; if (histblk < 1) histblk = 1;
            hist4_kernel<<<histblk, 256, 0, stream>>>(src, dst, cnt, E, N, S);
            norm_from_cnt_kernel<<<(2 * N + 255) / 256, 256, 0, stream>>>(cnt, norm, 2 * N, S);
            scan_blocks_kernel<<<nblk, SCAN_THREADS, 0, stream>>>(cnt + (size_t)N * S, offsets,
                                                                  partials, N, S);
            scan_partials_kernel<<<1, SCAN_THREADS, 0, stream>>>(partials, nblk);
            add_back_kernel<<<(N + 255) / 256, 256, 0, stream>>>(offsets, cursor, partials,
                                                                 N, E, S);
            bin4_kernel<<<histblk, 256, 0, stream>>>(src, dst, cursor, sorted_src, E, S);

            xw_tiled_kernel<<<(N + XW_ROWS - 1) / XW_ROWS, 256, 0, stream>>>(
                (const float4*)x, W, norm, y, N);
            int agg_blocks = (N + 3) / 4;
            agg_bf16_kernel<<<agg_blocks, 256, 0, stream>>>(
                (const uint4*)y, offsets, sorted_src, norm + N, (float4*)out, N);
            return;
        }
    }

    // ---- LAST-RESORT fallback (round 0): float-atomic scatter
    {
        float* deg = (float*)d_ws;
        float* agg = (float*)d_out;

        hipMemsetAsync(deg, 0, (size_t)2 * N * sizeof(float), stream);
        hipMemsetAsync(agg, 0, (size_t)N * D * sizeof(float), stream);

        deg_kernel<<<(E + 255) / 256, 256, 0, stream>>>(src, dst, deg, E, N);
        norm_kernel<<<(2 * N + 255) / 256, 256, 0, stream>>>(deg, 2 * N);

        long long scatter_threads = (long long)E * 16;
        int scatter_blocks = (int)((scatter_threads + 255) / 256);
        scatter_kernel<<<scatter_blocks, 256, 0, stream>>>(x, src, dst, deg, agg, E);

        const int rows_per_block = 64;
        int gemm_blocks = (N + rows_per_block - 1) / rows_per_block;
        gemm_kernel<<<gemm_blocks, 256, 0, stream>>>(agg, W, deg + N, N, rows_per_block);
    }
}